// Round 13
// baseline (96.977 us; speedup 1.0000x reference)
//
#include <hip/hip_runtime.h>

// PPO loss fused pipeline for MI355X (gfx950).
// R13: R6 (best occupancy 40%, best bench 65.9) + spill fix. R6's only defect
// was launch_bounds(512,4) forcing a 64-VGPR cap (empirical cap ~256/arg) onto
// a ~90-VGPR working set -> 10MB in-loop scratch. Now (512,2) -> cap 128.
// Structure unchanged: 1024 blocks x 512 thr (8 waves, 64 rows, wave=64x32,
// acc[4][2]=32 VGPR), LDS 72KB -> 2 blocks/CU = 16 waves, pre-swizzled B via
// global_load_lds DMA, 1 barrier/iter. Stats via k_gae4.

#define TT 65536

typedef float f32x4 __attribute__((ext_vector_type(4)));
typedef __bf16 bf16x8 __attribute__((ext_vector_type(8)));
typedef unsigned short u16x8 __attribute__((ext_vector_type(8)));

__device__ __forceinline__ unsigned short f2bf(float f) {
    unsigned int u = __float_as_uint(f);
    unsigned int r = (u + 0x7fffu + ((u >> 16) & 1u)) >> 16;
    return (unsigned short)r;
}

// hw packed fp32->bf16 (RTNE)
__device__ __forceinline__ unsigned int cvt_pk_bf16(float a, float b) {
    unsigned int r;
    asm("v_cvt_pk_bf16_f32 %0, %1, %2" : "=v"(r) : "v"(a), "v"(b));
    return r;
}

// branch-free tanh: 1 - 2/(e^{2x}+1)
__device__ __forceinline__ float fast_tanh(float x) {
    float e = __expf(2.0f * x);
    return fmaf(-2.0f, __builtin_amdgcn_rcpf(e + 1.0f), 1.0f);
}

__device__ __forceinline__ void async_lds16(void* lds, const void* g) {
    __builtin_amdgcn_global_load_lds(
        (const __attribute__((address_space(1))) unsigned int*)g,
        (__attribute__((address_space(3))) unsigned int*)lds, 16, 0, 0);
}

// ---------------- GAE affine suffix scan ----------------
__device__ __forceinline__ void suffix_scan256(float* sC, float* sD, int i) {
    float c = sC[i], d = sD[i];
#pragma unroll
    for (int s = 1; s < 256; s <<= 1) {
        float c2 = 1.0f, d2 = 0.0f;
        if (i + s < 256) { c2 = sC[i + s]; d2 = sD[i + s]; }
        __syncthreads();
        d = d + c * d2;
        c = c * c2;
        sC[i] = c; sD[i] = d;
        __syncthreads();
    }
}

__device__ __forceinline__ void gae_cd(const float* rewards, const float* terms,
                                       const float* values, int t, float* c, float* d) {
    float nt = 1.0f - terms[t];
    float nv = (t + 1 < TT) ? values[t + 1] : 0.0f;
    *d = rewards[t] + 0.99f * nv * nt - values[t];
    *c = 0.99f * 0.95f * nt;
}

// ---------------- fused prep + gae1 ----------------
// Pre-swizzled weight layouts for global_load_lds (verified on-device R6-R9):
//   W1T/W2T: per K-tile kt (8192 elems): chunk L in [0,1024), elem e:
//     row = L>>2, p = L&3, k = kt*32 + ((p ^ ((row>>1)&3))<<3) + e; val = W[k][row]
//   WavT (8192 elems): L: row = L>>5, ec = (L&31)<<3, k = (ec ^ ((row&7)<<3)) + e;
//     rows 0-15 = Wa^T, 16 = Wc^T, 17-31 = 0.
__global__ void k_prep_gae1(const float* __restrict__ W1, const float* __restrict__ W2,
                            const float* __restrict__ Wa, const float* __restrict__ Wc,
                            unsigned short* __restrict__ W1T, unsigned short* __restrict__ W2T,
                            unsigned short* __restrict__ WavT,
                            const float* __restrict__ rewards, const float* __restrict__ terms,
                            const float* __restrict__ values, float* __restrict__ aggC,
                            float* __restrict__ aggD) {
    if (blockIdx.x < 800) {
        int idx = blockIdx.x * 256 + threadIdx.x;
        if (idx < 131072) {
            int kt = idx >> 13;
            int L = (idx & 8191) >> 3, e = idx & 7;
            int row = L >> 2, p = L & 3;
            int k = kt * 32 + (((p ^ ((row >> 1) & 3)) << 3) | e);
            W1T[idx] = f2bf(W1[k * 256 + row]);
        } else if (idx < 196608) {
            int i = idx - 131072;
            int kt = i >> 13;
            int L = (i & 8191) >> 3, e = i & 7;
            int row = L >> 2, p = L & 3;
            int k = kt * 32 + (((p ^ ((row >> 1) & 3)) << 3) | e);
            W2T[i] = f2bf(W2[k * 256 + row]);
        } else if (idx < 204800) {
            int i = idx - 196608;
            int L = i >> 3, e = i & 7;
            int row = L >> 5, ec = (L & 31) << 3;
            int k = ((ec ^ ((row & 7) << 3)) | e);
            float v = (row < 16) ? Wa[k * 16 + row] : ((row == 16) ? Wc[k] : 0.0f);
            WavT[i] = f2bf(v);
        }
        return;
    }
    __shared__ float sC[256], sD[256];
    int i = threadIdx.x;
    int b = blockIdx.x - 800;
    int t = b * 256 + i;
    float c, d;
    gae_cd(rewards, terms, values, t, &c, &d);
    sC[i] = c; sD[i] = d;
    __syncthreads();
    suffix_scan256(sC, sD, i);
    if (i == 0) { aggC[b] = sC[0]; aggD[b] = sD[0]; }
}

// ---------------- gae3: carry + adv/ret + per-block sum partials ----------------
__global__ void k_gae3(const float* __restrict__ rewards, const float* __restrict__ terms,
                       const float* __restrict__ values, const float* __restrict__ aggC,
                       const float* __restrict__ aggD, float* __restrict__ adv,
                       float* __restrict__ ret, float* __restrict__ sumP) {
    __shared__ float sC[256], sD[256];
    int i = threadIdx.x, b = blockIdx.x;
    sC[i] = aggC[i]; sD[i] = aggD[i];
    __syncthreads();
    suffix_scan256(sC, sD, i);
    float carry = (b < 255) ? sD[b + 1] : 0.0f;
    __syncthreads();

    int t = b * 256 + i;
    float c, d;
    gae_cd(rewards, terms, values, t, &c, &d);
    sC[i] = c; sD[i] = d;
    __syncthreads();
    suffix_scan256(sC, sD, i);
    float a = sD[i] + sC[i] * carry;
    adv[t] = a;
    ret[t] = a + values[t];
    __syncthreads();
    sC[i] = a; sD[i] = a * a;
    __syncthreads();
#pragma unroll
    for (int s = 128; s > 0; s >>= 1) {
        if (i < s) { sC[i] += sC[i + s]; sD[i] += sD[i + s]; }
        __syncthreads();
    }
    if (i == 0) { sumP[2 * b] = sC[0]; sumP[2 * b + 1] = sD[0]; }
}

// ---------------- gae4: adv mean / rstd (1 block) ----------------
__global__ void k_gae4(const float* __restrict__ sumP, float* __restrict__ stats) {
    __shared__ float s1[256], s2[256];
    int i = threadIdx.x;
    s1[i] = sumP[2 * i]; s2[i] = sumP[2 * i + 1];
    __syncthreads();
#pragma unroll
    for (int s = 128; s > 0; s >>= 1) {
        if (i < s) { s1[i] += s1[i + s]; s2[i] += s2[i + s]; }
        __syncthreads();
    }
    if (i == 0) {
        float mean = s1[0] * (1.0f / TT);
        float var = s2[0] * (1.0f / TT) - mean * mean;
        stats[0] = mean;
        stats[1] = 1.0f / (sqrtf(fmaxf(var, 0.0f)) + 1e-8f);
    }
}

// ---------------- fused MLP + heads + loss (64 rows/block, 8 waves) ----------------
// Wave tile 64 rows x 32 cols: col offset = wid*32; acc[4][2] (32 VGPR).
// LDS (72KB): [0,32K) B dbuf (2x16K), [32K,40K) A dbuf (2x4K), [40K,72K) smH.
// Staged B/A tiles [R][32]: 16B slot' = slot ^ ((row>>1)&3).
// smH swizzle: elem' = elem ^ ((row&7)<<3).
// launch_bounds(512,2): empirical VGPR cap 128 (R6's (512,4) forced 64 -> spill).
__global__ __launch_bounds__(512, 2) void k_mlp(
    const float* __restrict__ obs, const int* __restrict__ actions,
    const float* __restrict__ logprobs, const float* __restrict__ values,
    const float* __restrict__ b1, const float* __restrict__ b2,
    const float* __restrict__ ba, const float* __restrict__ bc,
    const unsigned short* __restrict__ W1T, const unsigned short* __restrict__ W2T,
    const unsigned short* __restrict__ WavT, const float* __restrict__ adv,
    const float* __restrict__ ret, const float* __restrict__ stats,
    float* __restrict__ lossP) {
    __shared__ __align__(16) unsigned char SM[73728];
    unsigned short* smB = (unsigned short*)SM;                   // 2 x 8192 elems
    unsigned short* smA = (unsigned short*)(SM + 32768);         // 2 x 2048 elems
    unsigned short* smH = (unsigned short*)(SM + 40960);         // [64][256]
    float* red2 = (float*)(SM + 32768);                          // loss scratch (post-GEMM)

    const int tid = threadIdx.x;
    const int wid = tid >> 6;
    const int lane = tid & 63;
    const int cl = lane & 15;
    const int gg = lane >> 4;
    const int bm0 = blockIdx.x * 64;

    // A staging: 64x32 fp32, thread -> 4 floats (16B coalesced), 8B bf16 write
    const int arow = tid >> 3;                  // 0..63
    const int acol = (tid & 7) * 4;             // 0,4,..,28
    const int adst = arow * 32 +
        ((((acol >> 3) ^ ((arow >> 1) & 3)) << 3) | (acol & 4));
    const float* aSrc = obs + (size_t)(bm0 + arow) * 512 + acol;

    // issue tile-0 loads early
    float4 areg = *(const float4*)aSrc;
#pragma unroll
    for (int c = 0; c < 2; ++c) {
        int chunk = wid * 2 + c;
        async_lds16(&smB[chunk * 512], W1T + chunk * 512 + lane * 8);
    }

    const float meanA = stats[0], rstdA = stats[1];

    float b1v[2], b2v[2];
#pragma unroll
    for (int n = 0; n < 2; ++n) {
        int c = wid * 32 + n * 16 + cl;
        b1v[n] = b1[c];
        b2v[n] = b2[c];
    }
    const float bav = ba[cl];
    const float bc0 = bc[0];

    f32x4 acc[4][2];
#pragma unroll
    for (int m = 0; m < 4; ++m)
#pragma unroll
        for (int n = 0; n < 2; ++n) acc[m][n] = (f32x4){0.f, 0.f, 0.f, 0.f};

    auto writeA = [&](int buf) {
        uint2 p;
        p.x = cvt_pk_bf16(areg.x, areg.y);
        p.y = cvt_pk_bf16(areg.z, areg.w);
        *(uint2*)&smA[buf * 2048 + adst] = p;
    };

    // prologue: A tile 0 into LDS
    writeA(0);
    __syncthreads();   // also drains B tile-0 DMA

    // ---------------- GEMM1: hidden1 = tanh(obs @ W1 + b1), K=512, 16 tiles ----------------
#pragma unroll
    for (int t = 0; t < 16; ++t) {
        // stage t+1 (B via DMA from pre-swizzled layout; A via regs)
        const unsigned short* bsrc = (t < 15) ? (W1T + (t + 1) * 8192) : W2T;
#pragma unroll
        for (int c = 0; c < 2; ++c) {
            int chunk = wid * 2 + c;
            async_lds16(&smB[((t + 1) & 1) * 8192 + chunk * 512], bsrc + chunk * 512 + lane * 8);
        }
        if (t < 15) areg = *(const float4*)(aSrc + (t + 1) * 32);

        bf16x8 av[4], bv[2];
#pragma unroll
        for (int m = 0; m < 4; ++m) {
            int ra = m * 16 + cl;
            av[m] = *(const bf16x8*)&smA[(t & 1) * 2048 + ra * 32 + ((gg ^ ((ra >> 1) & 3)) << 3)];
        }
#pragma unroll
        for (int n = 0; n < 2; ++n) {
            int rb = wid * 32 + n * 16 + cl;
            bv[n] = *(const bf16x8*)&smB[(t & 1) * 8192 + rb * 32 + ((gg ^ ((rb >> 1) & 3)) << 3)];
        }
#pragma unroll
        for (int m = 0; m < 4; ++m)
#pragma unroll
            for (int n = 0; n < 2; ++n)
                acc[m][n] = __builtin_amdgcn_mfma_f32_16x16x32_bf16(av[m], bv[n], acc[m][n], 0, 0, 0);
        if (t < 15) writeA((t + 1) & 1);
        __syncthreads();
    }

    // epilogue 1: tanh + bias -> smH (swizzled), reset acc
#pragma unroll
    for (int m = 0; m < 4; ++m)
#pragma unroll
        for (int n = 0; n < 2; ++n)
#pragma unroll
            for (int j = 0; j < 4; ++j) {
                int r = m * 16 + gg * 4 + j;
                int c = wid * 32 + n * 16 + cl;
                smH[r * 256 + (c ^ ((r & 7) << 3))] = f2bf(fast_tanh(acc[m][n][j] + b1v[n]));
                acc[m][n][j] = 0.0f;
            }
    __syncthreads();   // hidden1 complete; smB buf0 holds W2T tile 0

    // ---------------- GEMM2: hidden = tanh(hidden1 @ W2 + b2), K=256, 8 tiles ----------------
#pragma unroll
    for (int t = 0; t < 8; ++t) {
        const unsigned short* bsrc = (t < 7) ? (W2T + (t + 1) * 8192) : WavT;
#pragma unroll
        for (int c = 0; c < 2; ++c) {
            int chunk = wid * 2 + c;
            async_lds16(&smB[((t + 1) & 1) * 8192 + chunk * 512], bsrc + chunk * 512 + lane * 8);
        }
        bf16x8 av[4], bv[2];
#pragma unroll
        for (int m = 0; m < 4; ++m) {
            int ra = m * 16 + cl;
            av[m] = *(const bf16x8*)&smH[ra * 256 + ((t * 32 + gg * 8) ^ ((ra & 7) << 3))];
        }
#pragma unroll
        for (int n = 0; n < 2; ++n) {
            int rb = wid * 32 + n * 16 + cl;
            bv[n] = *(const bf16x8*)&smB[(t & 1) * 8192 + rb * 32 + ((gg ^ ((rb >> 1) & 3)) << 3)];
        }
#pragma unroll
        for (int m = 0; m < 4; ++m)
#pragma unroll
            for (int n = 0; n < 2; ++n)
                acc[m][n] = __builtin_amdgcn_mfma_f32_16x16x32_bf16(av[m], bv[n], acc[m][n], 0, 0, 0);
        __syncthreads();
    }

    // epilogue 2: hidden -> smH; smB buf0 holds WavT [32][256] (smH-style swizzle)
#pragma unroll
    for (int m = 0; m < 4; ++m)
#pragma unroll
        for (int n = 0; n < 2; ++n)
#pragma unroll
            for (int j = 0; j < 4; ++j) {
                int r = m * 16 + gg * 4 + j;
                int c = wid * 32 + n * 16 + cl;
                smH[r * 256 + (c ^ ((r & 7) << 3))] = f2bf(fast_tanh(acc[m][n][j] + b2v[n]));
            }
    __syncthreads();

    // ---------------- heads + loss: waves 0..3 own rows [wid*16,+16) ----------------
    float lsum = 0.0f;
    if (wid < 4) {
        f32x4 acc_a = {0.f, 0.f, 0.f, 0.f}, acc_v = {0.f, 0.f, 0.f, 0.f};
#pragma unroll
        for (int kk = 0; kk < 8; ++kk) {
            int r = wid * 16 + cl;
            bf16x8 av = *(const bf16x8*)&smH[r * 256 + ((kk * 32 + gg * 8) ^ ((r & 7) << 3))];
            int ra2 = cl;
            bf16x8 bva = *(const bf16x8*)&smB[ra2 * 256 + ((kk * 32 + gg * 8) ^ ((ra2 & 7) << 3))];
            int rv = 16 + cl;
            bf16x8 bvv = *(const bf16x8*)&smB[rv * 256 + ((kk * 32 + gg * 8) ^ ((rv & 7) << 3))];
            acc_a = __builtin_amdgcn_mfma_f32_16x16x32_bf16(av, bva, acc_a, 0, 0, 0);
            acc_v = __builtin_amdgcn_mfma_f32_16x16x32_bf16(av, bvv, acc_v, 0, 0, 0);
        }

        const int t0 = bm0 + wid * 16;
#pragma unroll
        for (int j = 0; j < 4; ++j) {
            int t = t0 + gg * 4 + j;
            float lg = acc_a[j] + bav;
            float mx = lg;
#pragma unroll
            for (int dd = 1; dd < 16; dd <<= 1) mx = fmaxf(mx, __shfl_xor(mx, dd));
            float ex = __expf(lg - mx);
            float se = ex;
#pragma unroll
            for (int dd = 1; dd < 16; dd <<= 1) se += __shfl_xor(se, dd);
            float ls = __logf(se);
            float lp = lg - mx - ls;
            float pl = __expf(lp) * lp;
            float ent = pl;
#pragma unroll
            for (int dd = 1; dd < 16; dd <<= 1) ent += __shfl_xor(ent, dd);
            ent = -ent;
            int act = actions[t];
            float newlp = __shfl(lp, (lane & 48) | act);
            float val = __shfl(acc_v[j], lane & 48) + bc0;

            float lpo = logprobs[t];
            float at = (adv[t] - meanA) * rstdA;
            float rt = ret[t];
            float vo = values[t];
            float ratio = __expf(newlp - lpo);
            float rcl = fminf(fmaxf(ratio, 0.8f), 1.2f);
            float pg = fmaxf(-at * ratio, -at * rcl);
            float vcl = vo + fminf(fmaxf(val - vo, -0.2f), 0.2f);
            float dv = val - rt, dvc = vcl - rt;
            float vl = fmaxf(dv * dv, dvc * dvc);
            if (cl == 0) lsum += pg - 0.01f * ent + 0.25f * vl;
        }
        lsum += __shfl_xor(lsum, 16);
        lsum += __shfl_xor(lsum, 32);
    }
    __syncthreads();   // heads' smB reads done; smA region reusable as red2
    if (wid < 4 && lane == 0) red2[wid] = lsum;
    __syncthreads();
    if (tid == 0) lossP[blockIdx.x] = red2[0] + red2[1] + red2[2] + red2[3];
}

__global__ void k_final(const float* __restrict__ lossP, float* __restrict__ out) {
    __shared__ float s[256];
    int i = threadIdx.x;
    s[i] = lossP[i] + lossP[i + 256] + lossP[i + 512] + lossP[i + 768];
    __syncthreads();
#pragma unroll
    for (int st = 128; st > 0; st >>= 1) {
        if (i < st) s[i] += s[i + st];
        __syncthreads();
    }
    if (i == 0) out[0] = s[0] * (1.0f / TT);
}

extern "C" void kernel_launch(void* const* d_in, const int* in_sizes, int n_in,
                              void* d_out, int out_size, void* d_ws, size_t ws_size,
                              hipStream_t stream) {
    const float* obs      = (const float*)d_in[0];
    const int*   actions  = (const int*)d_in[1];
    const float* logprobs = (const float*)d_in[2];
    const float* rewards  = (const float*)d_in[3];
    const float* terms    = (const float*)d_in[4];
    const float* values   = (const float*)d_in[5];
    const float* W1 = (const float*)d_in[6];
    const float* b1 = (const float*)d_in[7];
    const float* W2 = (const float*)d_in[8];
    const float* b2 = (const float*)d_in[9];
    const float* Wa = (const float*)d_in[10];
    const float* ba = (const float*)d_in[11];
    const float* Wc = (const float*)d_in[12];
    const float* bc = (const float*)d_in[13];

    char* ws = (char*)d_ws;
    unsigned short* W1T  = (unsigned short*)(ws + 0);        // 262144 B
    unsigned short* W2T  = (unsigned short*)(ws + 262144);   // 131072 B
    unsigned short* WavT = (unsigned short*)(ws + 393216);   // 16384 B
    float* advp  = (float*)(ws + 409600);                    // 262144 B
    float* retp  = (float*)(ws + 671744);                    // 262144 B
    float* aggC  = (float*)(ws + 933888);                    // 1024 B
    float* aggD  = (float*)(ws + 934912);                    // 1024 B
    float* sumP  = (float*)(ws + 936960);                    // 2048 B
    float* stats = (float*)(ws + 939008);                    // 64 B
    float* lossP = (float*)(ws + 939072);                    // 4096 B

    k_prep_gae1<<<1056, 256, 0, stream>>>(W1, W2, Wa, Wc, W1T, W2T, WavT,
                                          rewards, terms, values, aggC, aggD);
    k_gae3<<<256, 256, 0, stream>>>(rewards, terms, values, aggC, aggD, advp, retp, sumP);
    k_gae4<<<1, 256, 0, stream>>>(sumP, stats);
    k_mlp<<<1024, 512, 0, stream>>>(obs, actions, logprobs, values, b1, b2, ba, bc,
                                    W1T, W2T, WavT, advp, retp, stats, lossP);
    k_final<<<1, 256, 0, stream>>>(lossP, (float*)d_out);
}

// Round 14
// 67.354 us; speedup vs baseline: 1.4398x; 1.4398x over previous
//
#include <hip/hip_runtime.h>

// PPO loss fused pipeline for MI355X (gfx950).
// R14: R12's k_mlp (tight-variance best family) + gae4 folded into k_mlp's
// prologue (per-block 512-float stats reduce, R6-style) -> 4 launches.
// Rationale: R6/R10/R12 (3 different k_mlp structures) all hit ~66 total ->
// bench is co-dominated by the serial kernel chain, not the MLP loop.

#define TT 65536

typedef float f32x4 __attribute__((ext_vector_type(4)));
typedef __bf16 bf16x8 __attribute__((ext_vector_type(8)));
typedef unsigned short u16x8 __attribute__((ext_vector_type(8)));
typedef unsigned int u32x4 __attribute__((ext_vector_type(4)));

__device__ __forceinline__ unsigned short f2bf(float f) {
    unsigned int u = __float_as_uint(f);
    unsigned int r = (u + 0x7fffu + ((u >> 16) & 1u)) >> 16;
    return (unsigned short)r;
}

// hw packed fp32->bf16 (RTNE)
__device__ __forceinline__ unsigned int cvt_pk_bf16(float a, float b) {
    unsigned int r;
    asm("v_cvt_pk_bf16_f32 %0, %1, %2" : "=v"(r) : "v"(a), "v"(b));
    return r;
}

// branch-free tanh: 1 - 2/(e^{2x}+1)
__device__ __forceinline__ float fast_tanh(float x) {
    float e = __expf(2.0f * x);
    return fmaf(-2.0f, __builtin_amdgcn_rcpf(e + 1.0f), 1.0f);
}

// LDS-visibility barrier (does not drain vmcnt)
__device__ __forceinline__ void lds_barrier() {
    asm volatile("s_waitcnt lgkmcnt(0)" ::: "memory");
    __builtin_amdgcn_s_barrier();
}

// ---------------- GAE affine suffix scan ----------------
__device__ __forceinline__ void suffix_scan256(float* sC, float* sD, int i) {
    float c = sC[i], d = sD[i];
#pragma unroll
    for (int s = 1; s < 256; s <<= 1) {
        float c2 = 1.0f, d2 = 0.0f;
        if (i + s < 256) { c2 = sC[i + s]; d2 = sD[i + s]; }
        __syncthreads();
        d = d + c * d2;
        c = c * c2;
        sC[i] = c; sD[i] = d;
        __syncthreads();
    }
}

__device__ __forceinline__ void gae_cd(const float* rewards, const float* terms,
                                       const float* values, int t, float* c, float* d) {
    float nt = 1.0f - terms[t];
    float nv = (t + 1 < TT) ? values[t + 1] : 0.0f;
    *d = rewards[t] + 0.99f * nv * nt - values[t];
    *c = 0.99f * 0.95f * nt;
}

// ---------------- fused prep + gae1 ----------------
// Fragment-major layouts (verified R10-R12):
//   frag (kt, nt): elem ((kt*16+nt)*64 + l)*8 + e = W[k = kt*32+(l>>4)*8+e][col = nt*16+(l&15)]
// Producer iterates col-within-k -> coalesced W reads.
__global__ void k_prep_gae1(const float* __restrict__ W1, const float* __restrict__ W2,
                            const float* __restrict__ Wa, const float* __restrict__ Wc,
                            unsigned short* __restrict__ W1Tf, unsigned short* __restrict__ W2Tf,
                            unsigned short* __restrict__ Wavf,
                            const float* __restrict__ rewards, const float* __restrict__ terms,
                            const float* __restrict__ values, float* __restrict__ aggC,
                            float* __restrict__ aggD) {
    if (blockIdx.x < 800) {
        int idx = blockIdx.x * 256 + threadIdx.x;
        if (idx < 131072) {
            int col = idx & 255, k = idx >> 8;            // coalesced read of W1[k][:]
            int kt = k >> 5, lh = (k & 31) >> 3, e = k & 7;
            int nt = col >> 4, cl = col & 15;
            W1Tf[(((kt * 16 + nt) * 64) + lh * 16 + cl) * 8 + e] = f2bf(W1[k * 256 + col]);
        } else if (idx < 196608) {
            int i = idx - 131072;
            int col = i & 255, k = i >> 8;
            int kt = k >> 5, lh = (k & 31) >> 3, e = k & 7;
            int nt = col >> 4, cl = col & 15;
            W2Tf[(((kt * 16 + nt) * 64) + lh * 16 + cl) * 8 + e] = f2bf(W2[k * 256 + col]);
        } else if (idx < 204800) {
            int i = idx - 196608;                          // [0,4096) Wa, [4096,8192) Wc
            if (i < 4096) {
                int a = i & 15, k = i >> 4;
                int kt = k >> 5, lh = (k & 31) >> 3, e = k & 7;
                Wavf[(((kt * 2 + 0) * 64) + lh * 16 + a) * 8 + e] = f2bf(Wa[k * 16 + a]);
            } else {
                int j = i - 4096;
                int a = j & 15, k = j >> 4;
                int kt = k >> 5, lh = (k & 31) >> 3, e = k & 7;
                float v = (a == 0) ? Wc[k] : 0.0f;
                Wavf[(((kt * 2 + 1) * 64) + lh * 16 + a) * 8 + e] = f2bf(v);
            }
        }
        return;
    }
    __shared__ float sC[256], sD[256];
    int i = threadIdx.x;
    int b = blockIdx.x - 800;
    int t = b * 256 + i;
    float c, d;
    gae_cd(rewards, terms, values, t, &c, &d);
    sC[i] = c; sD[i] = d;
    __syncthreads();
    suffix_scan256(sC, sD, i);
    if (i == 0) { aggC[b] = sC[0]; aggD[b] = sD[0]; }
}

// ---------------- gae3: carry + adv/ret + per-block sum partials ----------------
__global__ void k_gae3(const float* __restrict__ rewards, const float* __restrict__ terms,
                       const float* __restrict__ values, const float* __restrict__ aggC,
                       const float* __restrict__ aggD, float* __restrict__ adv,
                       float* __restrict__ ret, float* __restrict__ sumP) {
    __shared__ float sC[256], sD[256];
    int i = threadIdx.x, b = blockIdx.x;
    sC[i] = aggC[i]; sD[i] = aggD[i];
    __syncthreads();
    suffix_scan256(sC, sD, i);
    float carry = (b < 255) ? sD[b + 1] : 0.0f;
    __syncthreads();

    int t = b * 256 + i;
    float c, d;
    gae_cd(rewards, terms, values, t, &c, &d);
    sC[i] = c; sD[i] = d;
    __syncthreads();
    suffix_scan256(sC, sD, i);
    float a = sD[i] + sC[i] * carry;
    adv[t] = a;
    ret[t] = a + values[t];
    __syncthreads();
    sC[i] = a; sD[i] = a * a;
    __syncthreads();
#pragma unroll
    for (int s = 128; s > 0; s >>= 1) {
        if (i < s) { sC[i] += sC[i + s]; sD[i] += sD[i + s]; }
        __syncthreads();
    }
    if (i == 0) { sumP[2 * b] = sC[0]; sumP[2 * b + 1] = sD[0]; }
}

// ---------------- fused MLP + heads + loss (64 rows/block, 4 waves) ----------------
// LDS 64KB: smA [64][512] bf16 (whole obs tile, swizzled elem^((row&7)<<3));
// smH [64][256] overlays smA after GEMM1. No barriers inside any GEMM loop.
// Prologue: per-block adv-stats reduce (folds old gae4; removes one launch).
__global__ __launch_bounds__(256, 2) void k_mlp(
    const float* __restrict__ obs, const int* __restrict__ actions,
    const float* __restrict__ logprobs, const float* __restrict__ values,
    const float* __restrict__ b1, const float* __restrict__ b2,
    const float* __restrict__ ba, const float* __restrict__ bc,
    const unsigned short* __restrict__ W1Tf, const unsigned short* __restrict__ W2Tf,
    const unsigned short* __restrict__ Wavf, const float* __restrict__ adv,
    const float* __restrict__ ret, const float* __restrict__ sumP,
    float* __restrict__ lossP) {
    __shared__ __align__(16) unsigned char SM[65536];
    unsigned short* smA = (unsigned short*)SM;          // [64][512]
    unsigned short* smH = (unsigned short*)SM;          // [64][256] after GEMM1

    const int tid = threadIdx.x;
    const int wid = tid >> 6;
    const int lane = tid & 63;
    const int cl = lane & 15;
    const int gg = lane >> 4;
    const int bm0 = blockIdx.x * 64;

    // ---- adv stats (folds old gae4): 512-float reduce in LDS ----
    float meanA, rstdA;
    {
        float* red = (float*)SM;
        red[tid] = sumP[2 * tid];
        red[256 + tid] = sumP[2 * tid + 1];
        __syncthreads();
#pragma unroll
        for (int s = 128; s > 0; s >>= 1) {
            if (tid < s) { red[tid] += red[tid + s]; red[256 + tid] += red[256 + tid + s]; }
            __syncthreads();
        }
        meanA = red[0] * (1.0f / TT);
        float var = red[256] * (1.0f / TT) - meanA * meanA;
        rstdA = 1.0f / (sqrtf(fmaxf(var, 0.0f)) + 1e-8f);
        __syncthreads();   // red reads done before smA staging overwrites
    }

    float b1v[4], b2v[4];
#pragma unroll
    for (int n = 0; n < 4; ++n) {
        int c = wid * 64 + n * 16 + cl;
        b1v[n] = b1[c];
        b2v[n] = b2[c];
    }
    const float bav = ba[cl];
    const float bc0 = bc[0];

    // ---- one-shot A staging: 64 rows x 512 cols fp32 -> bf16, swizzled ----
    {
        const int arow = tid >> 2;              // 0..63
        const int acl4 = (tid & 3) * 8;         // 0,8,16,24
        const int axor = (arow & 7) << 3;
        const float* aSrc = obs + (size_t)(bm0 + arow) * 512 + acl4;
        unsigned short* aDst = smA + arow * 512;
#pragma unroll
        for (int ct = 0; ct < 16; ++ct) {
            float4 f0 = *(const float4*)(aSrc + ct * 32);
            float4 f1 = *(const float4*)(aSrc + ct * 32 + 4);
            u32x4 pk;
            pk[0] = cvt_pk_bf16(f0.x, f0.y);
            pk[1] = cvt_pk_bf16(f0.z, f0.w);
            pk[2] = cvt_pk_bf16(f1.x, f1.y);
            pk[3] = cvt_pk_bf16(f1.z, f1.w);
            *(u32x4*)&aDst[(ct * 32 + acl4) ^ axor] = pk;
        }
    }

    f32x4 acc[4][4];
#pragma unroll
    for (int m = 0; m < 4; ++m)
#pragma unroll
        for (int n = 0; n < 4; ++n) acc[m][n] = (f32x4){0.f, 0.f, 0.f, 0.f};

    // prefetch GEMM1 tile-0 B-frags (global; survives the lds_barrier in regs)
    const unsigned short* b1Base = W1Tf + ((size_t)(wid * 4) << 9) + lane * 8;
    bf16x8 bv0[4];
#pragma unroll
    for (int n = 0; n < 4; ++n)
        bv0[n] = *(const bf16x8*)(b1Base + ((size_t)n << 9));

    lds_barrier();   // A tile visible

    // ---------------- GEMM1: K=512, 16 tiles — NO barriers ----------------
#pragma unroll
    for (int t = 0; t < 16; ++t) {
        bf16x8 av[4], bv[4];
#pragma unroll
        for (int n = 0; n < 4; ++n)
            bv[n] = (t == 0) ? bv0[n]
                             : *(const bf16x8*)(b1Base + ((size_t)(t * 16 + n) << 9));
#pragma unroll
        for (int m = 0; m < 4; ++m) {
            int ra = m * 16 + cl;
            av[m] = *(const bf16x8*)&smA[ra * 512 + ((t * 32 + gg * 8) ^ ((ra & 7) << 3))];
        }
#pragma unroll
        for (int m = 0; m < 4; ++m)
#pragma unroll
            for (int n = 0; n < 4; ++n)
                acc[m][n] = __builtin_amdgcn_mfma_f32_16x16x32_bf16(av[m], bv[n], acc[m][n], 0, 0, 0);
    }

    // prefetch GEMM2 tile-0 B-frags before the phase barrier
    const unsigned short* b2Base = W2Tf + ((size_t)(wid * 4) << 9) + lane * 8;
#pragma unroll
    for (int n = 0; n < 4; ++n)
        bv0[n] = *(const bf16x8*)(b2Base + ((size_t)n << 9));

    lds_barrier();   // all GEMM1 smA reads done -> safe to overlay smH

    // epilogue 1: tanh -> smH (swizzled), reset acc
#pragma unroll
    for (int m = 0; m < 4; ++m)
#pragma unroll
        for (int n = 0; n < 4; ++n)
#pragma unroll
            for (int j = 0; j < 4; ++j) {
                int r = m * 16 + gg * 4 + j;
                int c = wid * 64 + n * 16 + cl;
                smH[r * 256 + (c ^ ((r & 7) << 3))] = f2bf(fast_tanh(acc[m][n][j] + b1v[n]));
                acc[m][n][j] = 0.0f;
            }
    lds_barrier();   // hidden1 visible

    // ---------------- GEMM2: K=256, 8 tiles — NO barriers ----------------
#pragma unroll
    for (int t = 0; t < 8; ++t) {
        bf16x8 av[4], bv[4];
#pragma unroll
        for (int n = 0; n < 4; ++n)
            bv[n] = (t == 0) ? bv0[n]
                             : *(const bf16x8*)(b2Base + ((size_t)(t * 16 + n) << 9));
#pragma unroll
        for (int m = 0; m < 4; ++m) {
            int ra = m * 16 + cl;
            av[m] = *(const bf16x8*)&smH[ra * 256 + ((t * 32 + gg * 8) ^ ((ra & 7) << 3))];
        }
#pragma unroll
        for (int m = 0; m < 4; ++m)
#pragma unroll
            for (int n = 0; n < 4; ++n)
                acc[m][n] = __builtin_amdgcn_mfma_f32_16x16x32_bf16(av[m], bv[n], acc[m][n], 0, 0, 0);
    }

    lds_barrier();   // all GEMM2 smH reads done -> safe to overwrite in place

    // epilogue 2: hidden -> smH
#pragma unroll
    for (int m = 0; m < 4; ++m)
#pragma unroll
        for (int n = 0; n < 4; ++n)
#pragma unroll
            for (int j = 0; j < 4; ++j) {
                int r = m * 16 + gg * 4 + j;
                int c = wid * 64 + n * 16 + cl;
                smH[r * 256 + (c ^ ((r & 7) << 3))] = f2bf(fast_tanh(acc[m][n][j] + b2v[n]));
            }
    lds_barrier();   // hidden2 visible

    // ---------------- heads + loss: wave wid owns rows [wid*16, +16) — NO barriers ----------------
    float lsum = 0.0f;
    {
        f32x4 acc_a = {0.f, 0.f, 0.f, 0.f}, acc_v = {0.f, 0.f, 0.f, 0.f};
        const unsigned short* wBase = Wavf + lane * 8;
#pragma unroll
        for (int kk = 0; kk < 8; ++kk) {
            int r = wid * 16 + cl;
            bf16x8 av = *(const bf16x8*)&smH[r * 256 + ((kk * 32 + gg * 8) ^ ((r & 7) << 3))];
            bf16x8 bva = *(const bf16x8*)(wBase + ((size_t)(kk * 2) << 9));
            bf16x8 bvv = *(const bf16x8*)(wBase + ((size_t)(kk * 2 + 1) << 9));
            acc_a = __builtin_amdgcn_mfma_f32_16x16x32_bf16(av, bva, acc_a, 0, 0, 0);
            acc_v = __builtin_amdgcn_mfma_f32_16x16x32_bf16(av, bvv, acc_v, 0, 0, 0);
        }

        const int t0 = bm0 + wid * 16;
#pragma unroll
        for (int j = 0; j < 4; ++j) {
            int t = t0 + gg * 4 + j;
            float lg = acc_a[j] + bav;
            float mx = lg;
#pragma unroll
            for (int dd = 1; dd < 16; dd <<= 1) mx = fmaxf(mx, __shfl_xor(mx, dd));
            float ex = __expf(lg - mx);
            float se = ex;
#pragma unroll
            for (int dd = 1; dd < 16; dd <<= 1) se += __shfl_xor(se, dd);
            float ls = __logf(se);
            float lp = lg - mx - ls;
            float pl = __expf(lp) * lp;
            float ent = pl;
#pragma unroll
            for (int dd = 1; dd < 16; dd <<= 1) ent += __shfl_xor(ent, dd);
            ent = -ent;
            int act = actions[t];
            float newlp = __shfl(lp, (lane & 48) | act);
            float val = __shfl(acc_v[j], lane & 48) + bc0;

            float lpo = logprobs[t];
            float at = (adv[t] - meanA) * rstdA;
            float rt = ret[t];
            float vo = values[t];
            float ratio = __expf(newlp - lpo);
            float rcl = fminf(fmaxf(ratio, 0.8f), 1.2f);
            float pg = fmaxf(-at * ratio, -at * rcl);
            float vcl = vo + fminf(fmaxf(val - vo, -0.2f), 0.2f);
            float dv = val - rt, dvc = vcl - rt;
            float vl = fmaxf(dv * dv, dvc * dvc);
            if (cl == 0) lsum += pg - 0.01f * ent + 0.25f * vl;
        }
        lsum += __shfl_xor(lsum, 16);
        lsum += __shfl_xor(lsum, 32);
    }
    lds_barrier();   // all smH reads done; reuse SM for final reduce
    float* red2 = (float*)SM;
    if (lane == 0) red2[wid] = lsum;
    lds_barrier();
    if (tid == 0) lossP[blockIdx.x] = red2[0] + red2[1] + red2[2] + red2[3];
}

__global__ void k_final(const float* __restrict__ lossP, float* __restrict__ out) {
    __shared__ float s[256];
    int i = threadIdx.x;
    s[i] = lossP[i] + lossP[i + 256] + lossP[i + 512] + lossP[i + 768];
    __syncthreads();
#pragma unroll
    for (int st = 128; st > 0; st >>= 1) {
        if (i < st) s[i] += s[i + st];
        __syncthreads();
    }
    if (i == 0) out[0] = s[0] * (1.0f / TT);
}

extern "C" void kernel_launch(void* const* d_in, const int* in_sizes, int n_in,
                              void* d_out, int out_size, void* d_ws, size_t ws_size,
                              hipStream_t stream) {
    const float* obs      = (const float*)d_in[0];
    const int*   actions  = (const int*)d_in[1];
    const float* logprobs = (const float*)d_in[2];
    const float* rewards  = (const float*)d_in[3];
    const float* terms    = (const float*)d_in[4];
    const float* values   = (const float*)d_in[5];
    const float* W1 = (const float*)d_in[6];
    const float* b1 = (const float*)d_in[7];
    const float* W2 = (const float*)d_in[8];
    const float* b2 = (const float*)d_in[9];
    const float* Wa = (const float*)d_in[10];
    const float* ba = (const float*)d_in[11];
    const float* Wc = (const float*)d_in[12];
    const float* bc = (const float*)d_in[13];

    char* ws = (char*)d_ws;
    unsigned short* W1Tf = (unsigned short*)(ws + 0);        // 262144 B
    unsigned short* W2Tf = (unsigned short*)(ws + 262144);   // 131072 B
    unsigned short* Wavf = (unsigned short*)(ws + 393216);   // 16384 B
    float* advp  = (float*)(ws + 409600);                    // 262144 B
    float* retp  = (float*)(ws + 671744);                    // 262144 B
    float* aggC  = (float*)(ws + 933888);                    // 1024 B
    float* aggD  = (float*)(ws + 934912);                    // 1024 B
    float* sumP  = (float*)(ws + 936960);                    // 2048 B
    float* lossP = (float*)(ws + 939072);                    // 4096 B

    k_prep_gae1<<<1056, 256, 0, stream>>>(W1, W2, Wa, Wc, W1Tf, W2Tf, Wavf,
                                          rewards, terms, values, aggC, aggD);
    k_gae3<<<256, 256, 0, stream>>>(rewards, terms, values, aggC, aggD, advp, retp, sumP);
    k_mlp<<<1024, 256, 0, stream>>>(obs, actions, logprobs, values, b1, b2, ba, bc,
                                    W1Tf, W2Tf, Wavf, advp, retp, sumP, lossP);
    k_final<<<1, 256, 0, stream>>>(lossP, (float*)d_out);
}